// Round 14
// baseline (969.433 us; speedup 1.0000x reference)
//
#include <hip/hip_runtime.h>
#include <hip/hip_bf16.h>

typedef __bf16 bf16_t;
typedef __bf16 bf16x8 __attribute__((ext_vector_type(8)));
typedef float f32x4 __attribute__((ext_vector_type(4)));

#define T_TOK 25216
#define C_DIM 768
#define NH 12
#define LSEQ 197

__device__ __forceinline__ void gload_lds16(const bf16_t* g, bf16_t* l) {
  __builtin_amdgcn_global_load_lds(
      (const __attribute__((address_space(1))) unsigned int*)g,
      (__attribute__((address_space(3))) unsigned int*)l, 16, 0, 0);
}

template <int N>
__device__ __forceinline__ void vm_wait() {
  asm volatile("s_waitcnt vmcnt(%0)" ::"n"(N) : "memory");
}
__device__ __forceinline__ void block_bar() {
  __builtin_amdgcn_sched_barrier(0);
  asm volatile("" ::: "memory");
  __builtin_amdgcn_s_barrier();
  __builtin_amdgcn_sched_barrier(0);
}

// -------- merged weight prep: all transposes in one launch -------------------
__device__ __forceinline__ void wtrans_body(const float* __restrict__ W,
                                            bf16_t* __restrict__ Wt, int K,
                                            int N, int bx, int by) {
  __shared__ float tile[32][33];
  const int tx = threadIdx.x, ty = threadIdx.y;
#pragma unroll
  for (int i = ty; i < 32; i += 8)
    tile[i][tx] = W[(long)(by * 32 + i) * N + bx * 32 + tx];
  __syncthreads();
#pragma unroll
  for (int i = ty; i < 32; i += 8)
    Wt[(long)(bx * 32 + i) * K + by * 32 + tx] = (bf16_t)tile[tx][i];
}

__global__ void wprep_k(const float* __restrict__ Wq,
                        const float* __restrict__ Wk,
                        const float* __restrict__ Wv,
                        const float* __restrict__ Wo,
                        const float* __restrict__ W1,
                        const float* __restrict__ W2,
                        bf16_t* __restrict__ Wqkvt, bf16_t* __restrict__ Wot,
                        bf16_t* __restrict__ W1t, bf16_t* __restrict__ W2t) {
  const int b = blockIdx.x;
  if (b < 2304) {  // 4x 768x768 (24x24 each)
    const int z = b / 576, r = b % 576;
    const float* W = z == 0 ? Wq : (z == 1 ? Wk : (z == 2 ? Wv : Wo));
    bf16_t* Wt = z == 3 ? Wot : Wqkvt + (size_t)z * 768 * 768;
    wtrans_body(W, Wt, 768, 768, r % 24, r / 24);
  } else if (b < 4608) {  // W1: K=768, N=3072 (96x24)
    const int r = b - 2304;
    wtrans_body(W1, W1t, 768, 3072, r % 96, r / 96);
  } else {  // W2: K=3072, N=768 (24x96)
    const int r = b - 4608;
    wtrans_body(W2, W2t, 3072, 768, r % 24, r / 24);
  }
}

__global__ void cat3_k(const float* __restrict__ a, const float* __restrict__ b,
                       const float* __restrict__ c, float* __restrict__ o) {
  int i = blockIdx.x * 256 + threadIdx.x;
  if (i < 2304) o[i] = i < 768 ? a[i] : (i < 1536 ? b[i - 768] : c[i - 1536]);
}

// ---------------- LayerNorm fp32 -> bf16, one wave per row -------------------
__global__ __launch_bounds__(256) void ln_k(const float* __restrict__ x,
                                            const float* __restrict__ g,
                                            const float* __restrict__ b,
                                            bf16_t* __restrict__ o) {
  const int lane = threadIdx.x & 63;
  const long row = (long)blockIdx.x * 4 + (threadIdx.x >> 6);
  const float* xr = x + row * C_DIM;
  float4 v[3];
  float s = 0.f, sq = 0.f;
#pragma unroll
  for (int i = 0; i < 3; ++i) {
    v[i] = *(const float4*)&xr[i * 256 + lane * 4];
    s += v[i].x + v[i].y + v[i].z + v[i].w;
    sq += v[i].x * v[i].x + v[i].y * v[i].y + v[i].z * v[i].z + v[i].w * v[i].w;
  }
#pragma unroll
  for (int off = 32; off; off >>= 1) {
    s += __shfl_xor(s, off);
    sq += __shfl_xor(sq, off);
  }
  const float mu = s * (1.f / 768.f);
  const float rstd = rsqrtf(sq * (1.f / 768.f) - mu * mu + 1e-5f);
  bf16_t* orow = o + row * C_DIM;
#pragma unroll
  for (int i = 0; i < 3; ++i) {
    const int c = i * 256 + lane * 4;
    const float4 gg = *(const float4*)&g[c];
    const float4 bb = *(const float4*)&b[c];
    bf16_t t4[4];
    t4[0] = (bf16_t)((v[i].x - mu) * rstd * gg.x + bb.x);
    t4[1] = (bf16_t)((v[i].y - mu) * rstd * gg.y + bb.y);
    t4[2] = (bf16_t)((v[i].z - mu) * rstd * gg.z + bb.z);
    t4[3] = (bf16_t)((v[i].w - mu) * rstd * gg.w + bb.w);
    __builtin_memcpy(&orow[c], t4, 8);
  }
}

// ---------------- GEMM: C[M,N] = A[M,K] @ Bt[N,K]^T + bias (+res) ------------
// R8 skeleton (verified): BK=64, 4 waves, T1 XCD swizzle + T2 XOR swizzle
// (0 conflicts verified) + T4 counted vmcnt ping-pong (no drain in-loop).
// This round: BN=192 (wave tile 64x96) — discriminating probe between the
// "throughput-invariant" and "per-tile fixed cost" models.
// EPI 0: bf16 out (bias). EPI 1: f32 out (bias + res). EPI 2: bf16 QuickGELU.
template <int EPI, int BM, int BN>
__global__ __launch_bounds__(256) void gemm_bt(
    const bf16_t* __restrict__ A, const bf16_t* __restrict__ Bt,
    const float* __restrict__ bias, const float* __restrict__ res,
    void* __restrict__ outp, int K, int N) {
  constexpr int MACC = BM / 32;  // per-wave 16x16 frags in M (wave owns BM/2)
  constexpr int NACC = BN / 32;  // per-wave 16x16 frags in N (wave owns BN/2)
  constexpr int ACW = BM / 32;   // A gload calls per wave (8 rows each)
  constexpr int BCW = BN / 32;   // B gload calls per wave
  constexpr int NLOADS = ACW + BCW;  // vmem ops per stage per wave
  __shared__ __align__(16) bf16_t lA[2][BM * 64];
  __shared__ __align__(16) bf16_t lB[2][BN * 64];
  const int tid = threadIdx.x;
  const int wave = tid >> 6, lane = tid & 63;
  const int fr = lane & 15, fq = lane >> 4;

  // bijective XCD-chunked swizzle (m204): hw id -> contiguous per-XCD chunks
  const int gx = gridDim.x;
  const int nwg = gridDim.x * gridDim.y;
  int bid = blockIdx.y * gx + blockIdx.x;
  {
    const int q = nwg >> 3, r = nwg & 7;
    const int xcd = bid & 7, idx = bid >> 3;
    bid = (xcd < r ? xcd * (q + 1) : r * (q + 1) + (xcd - r) * q) + idx;
  }
  const int bx = bid % gx, by = bid / gx;

  const long rowBase = (long)by * BM;
  const long colBase = (long)bx * BN;
  const int wr = (wave >> 1) * (BM / 2), wc = (wave & 1) * (BN / 2);

  f32x4 acc[MACC][NACC];
#pragma unroll
  for (int m = 0; m < MACC; ++m)
#pragma unroll
    for (int n = 0; n < NACC; ++n) acc[m][n] = (f32x4){0.f, 0.f, 0.f, 0.f};

  const int srow = lane >> 3;  // 0..7
  // inverse-swizzled global source chunk: LDS slot (srow, lane&7) receives
  // global chunk (lane&7)^srow, so LDS[row][c] = global[row][c ^ (row&7)].
  const int scol = (((lane & 7) ^ srow)) * 8;  // elems

  // per-thread staging base pointers (advance by koff elems per K-step)
  const bf16_t* aP[ACW];
  const bf16_t* bP[BCW];
#pragma unroll
  for (int c = 0; c < ACW; ++c)
    aP[c] = A + (rowBase + 8 * (wave * ACW + c) + srow) * (long)K + scol;
#pragma unroll
  for (int c = 0; c < BCW; ++c)
    bP[c] = Bt + (colBase + 8 * (wave * BCW + c) + srow) * (long)K + scol;

  auto stage0 = [&](int koff) {
#pragma unroll
    for (int c = 0; c < ACW; ++c)
      gload_lds16(aP[c] + koff, &lA[0][(wave * ACW + c) * 512]);
#pragma unroll
    for (int c = 0; c < BCW; ++c)
      gload_lds16(bP[c] + koff, &lB[0][(wave * BCW + c) * 512]);
  };
  auto stage1 = [&](int koff) {
#pragma unroll
    for (int c = 0; c < ACW; ++c)
      gload_lds16(aP[c] + koff, &lA[1][(wave * ACW + c) * 512]);
#pragma unroll
    for (int c = 0; c < BCW; ++c)
      gload_lds16(bP[c] + koff, &lB[1][(wave * BCW + c) * 512]);
  };
  auto compute0 = [&]() {
#pragma unroll
    for (int kf = 0; kf < 2; ++kf) {
      bf16x8 af[MACC], bfr[NACC];
#pragma unroll
      for (int m = 0; m < MACC; ++m) {
        const int row = wr + m * 16 + fr;
        af[m] =
            *(const bf16x8*)&lA[0][row * 64 + (((kf * 4 + fq) ^ (fr & 7)) * 8)];
      }
#pragma unroll
      for (int n = 0; n < NACC; ++n) {
        const int row = wc + n * 16 + fr;
        bfr[n] =
            *(const bf16x8*)&lB[0][row * 64 + (((kf * 4 + fq) ^ (fr & 7)) * 8)];
      }
#pragma unroll
      for (int m = 0; m < MACC; ++m)
#pragma unroll
        for (int n = 0; n < NACC; ++n)
          acc[m][n] = __builtin_amdgcn_mfma_f32_16x16x32_bf16(af[m], bfr[n],
                                                              acc[m][n], 0, 0, 0);
    }
  };
  auto compute1 = [&]() {
#pragma unroll
    for (int kf = 0; kf < 2; ++kf) {
      bf16x8 af[MACC], bfr[NACC];
#pragma unroll
      for (int m = 0; m < MACC; ++m) {
        const int row = wr + m * 16 + fr;
        af[m] =
            *(const bf16x8*)&lA[1][row * 64 + (((kf * 4 + fq) ^ (fr & 7)) * 8)];
      }
#pragma unroll
      for (int n = 0; n < NACC; ++n) {
        const int row = wc + n * 16 + fr;
        bfr[n] =
            *(const bf16x8*)&lB[1][row * 64 + (((kf * 4 + fq) ^ (fr & 7)) * 8)];
      }
#pragma unroll
      for (int m = 0; m < MACC; ++m)
#pragma unroll
        for (int n = 0; n < NACC; ++n)
          acc[m][n] = __builtin_amdgcn_mfma_f32_16x16x32_bf16(af[m], bfr[n],
                                                              acc[m][n], 0, 0, 0);
    }
  };

  const int kT = K >> 6;  // 12 or 48 (even)
  stage0(0);
  // main loop: buf0 holds tile kt, buf1 gets kt+1; counted vmcnt, no drain.
  int kt = 0;
  for (; kt + 2 < kT; kt += 2) {
    stage1((kt + 1) * 64);   // prefetch kt+1 (in flight across barriers)
    vm_wait<NLOADS>();       // my tile-kt loads done (prefetch outstanding)
    block_bar();             // => ALL waves' tile-kt loads done
    compute0();
    block_bar();             // buf0 reads done everywhere -> safe to overwrite
    stage0((kt + 2) * 64);   // prefetch kt+2
    vm_wait<NLOADS>();       // tile-(kt+1) loads done
    block_bar();
    compute1();
    block_bar();             // buf1 reads done -> next iter may overwrite
  }
  // tail: kt == kT-2; buf0 holds kT-2
  stage1((kt + 1) * 64);
  vm_wait<NLOADS>();
  block_bar();
  compute0();
  vm_wait<0>();  // drain last prefetch (only remaining vmem)
  block_bar();
  compute1();

#pragma unroll
  for (int m = 0; m < MACC; ++m) {
    const long row0 = rowBase + wr + m * 16 + fq * 4;
#pragma unroll
    for (int n = 0; n < NACC; ++n) {
      const long col = colBase + wc + n * 16 + fr;
      const float bb = bias[col];
#pragma unroll
      for (int r = 0; r < 4; ++r) {
        const long idx = (row0 + r) * N + col;
        float v = acc[m][n][r] + bb;
        if (EPI == 0) {
          ((bf16_t*)outp)[idx] = (bf16_t)v;
        } else if (EPI == 1) {
          ((float*)outp)[idx] = v + res[idx];
        } else {
          v = v / (1.f + __expf(-1.702f * v));
          ((bf16_t*)outp)[idx] = (bf16_t)v;
        }
      }
    }
  }
}

// ---------------- attention: one block per (batch, head) ---------------------
// qkv [T][2304] bf16 (q|k|v per token). mix [T][768] bf16 output.
__global__ __launch_bounds__(256) void attn_k(const bf16_t* __restrict__ qkv,
                                              bf16_t* __restrict__ mix) {
  constexpr int KR = 72;   // lK row stride (elems): 144B -> 2-way banks, 16B aligned
  constexpr int VR = 232;  // lVt/lP row stride: 464B -> 2-way banks, 16B aligned
  __shared__ __align__(16) bf16_t smem[208 * KR + 64 * VR + 64 * VR];
  bf16_t* lK = smem;
  bf16_t* lVt = smem + 208 * KR;
  bf16_t* lP = lVt + 64 * VR;

  const int tid = threadIdx.x;
  const int wave = tid >> 6, lane = tid & 63;
  const int fr = lane & 15, fq = lane >> 4;
  const int nh = blockIdx.x;
  const int n = nh / NH, h = nh % NH;
  const long t0 = (long)n * LSEQ;
  const long qs = 2304;

  {  // zero all LDS (covers K rows >=197, V cols >=197, P cols >= 208)
    int4 z = {0, 0, 0, 0};
    int4* p = (int4*)smem;
    const int tot = (208 * KR + 2 * 64 * VR) * 2 / 16;
    for (int i = tid; i < tot; i += 256) p[i] = z;
  }
  __syncthreads();

  for (int it = tid; it < 197 * 8; it += 256) {  // K rows
    int r = it >> 3, cg = it & 7;
    int4 v = *(const int4*)(qkv + (t0 + r) * qs + 768 + h * 64 + cg * 8);
    *(int4*)&lK[r * KR + cg * 8] = v;
  }
  for (int it = tid; it < 197 * 8; it += 256) {  // V transpose
    int r = it >> 3, cg = it & 7;
    int4 v = *(const int4*)(qkv + (t0 + r) * qs + 1536 + h * 64 + cg * 8);
    const bf16_t* pv = (const bf16_t*)&v;
#pragma unroll
    for (int j = 0; j < 8; ++j) lVt[(cg * 8 + j) * VR + r] = pv[j];
  }
  __syncthreads();

  bf16_t* lPw = lP + wave * 16 * VR;

  for (int fi = 0; fi < 4; ++fi) {
    const int f = wave + fi * 4;
    if (f >= 13) break;
    const int qrow = f * 16 + fr;
    const long tq = t0 + (qrow < LSEQ ? qrow : LSEQ - 1);
    const bf16_t* qp = qkv + tq * qs + h * 64;
    bf16x8 a0 = *(const bf16x8*)(qp + fq * 8);
    bf16x8 a1 = *(const bf16x8*)(qp + 32 + fq * 8);

    f32x4 s[13];
#pragma unroll
    for (int j = 0; j < 13; ++j) s[j] = (f32x4){0.f, 0.f, 0.f, 0.f};
#pragma unroll
    for (int j = 0; j < 13; ++j) {
      bf16x8 b0 = *(const bf16x8*)&lK[(j * 16 + fr) * KR + fq * 8];
      s[j] = __builtin_amdgcn_mfma_f32_16x16x32_bf16(a0, b0, s[j], 0, 0, 0);
      bf16x8 b1 = *(const bf16x8*)&lK[(j * 16 + fr) * KR + 32 + fq * 8];
      s[j] = __builtin_amdgcn_mfma_f32_16x16x32_bf16(a1, b1, s[j], 0, 0, 0);
    }
    // wave-parallel softmax over keys (row = fq*4+r, key = j*16 + lane&15)
    float mx[4] = {-3e38f, -3e38f, -3e38f, -3e38f};
#pragma unroll
    for (int j = 0; j < 13; ++j) {
      const bool valid = (j * 16 + fr) < LSEQ;
#pragma unroll
      for (int r = 0; r < 4; ++r) {
        float v = s[j][r] * 0.125f;
        v = valid ? v : -3e38f;
        s[j][r] = v;
        mx[r] = fmaxf(mx[r], v);
      }
    }
#pragma unroll
    for (int r = 0; r < 4; ++r) {
      mx[r] = fmaxf(mx[r], __shfl_xor(mx[r], 1));
      mx[r] = fmaxf(mx[r], __shfl_xor(mx[r], 2));
      mx[r] = fmaxf(mx[r], __shfl_xor(mx[r], 4));
      mx[r] = fmaxf(mx[r], __shfl_xor(mx[r], 8));
    }
    float sm[4] = {0.f, 0.f, 0.f, 0.f};
#pragma unroll
    for (int j = 0; j < 13; ++j)
#pragma unroll
      for (int r = 0; r < 4; ++r) {
        float e = __expf(s[j][r] - mx[r]);
        s[j][r] = e;
        sm[r] += e;
      }
#pragma unroll
    for (int r = 0; r < 4; ++r) {
      sm[r] += __shfl_xor(sm[r], 1);
      sm[r] += __shfl_xor(sm[r], 2);
      sm[r] += __shfl_xor(sm[r], 4);
      sm[r] += __shfl_xor(sm[r], 8);
      sm[r] = 1.f / sm[r];
    }
#pragma unroll
    for (int j = 0; j < 13; ++j)
#pragma unroll
      for (int r = 0; r < 4; ++r)
        lPw[(fq * 4 + r) * VR + j * 16 + fr] = (bf16_t)(s[j][r] * sm[r]);
    asm volatile("s_waitcnt lgkmcnt(0)" ::: "memory");

    f32x4 o4[4];
#pragma unroll
    for (int c = 0; c < 4; ++c) o4[c] = (f32x4){0.f, 0.f, 0.f, 0.f};
#pragma unroll
    for (int kc = 0; kc < 7; ++kc) {
      bf16x8 pa = *(const bf16x8*)&lPw[fr * VR + kc * 32 + fq * 8];
#pragma unroll
      for (int c = 0; c < 4; ++c) {
        bf16x8 bv = *(const bf16x8*)&lVt[(c * 16 + fr) * VR + kc * 32 + fq * 8];
        o4[c] = __builtin_amdgcn_mfma_f32_16x16x32_bf16(pa, bv, o4[c], 0, 0, 0);
      }
    }
#pragma unroll
    for (int c = 0; c < 4; ++c)
#pragma unroll
      for (int r = 0; r < 4; ++r) {
        const int q = f * 16 + fq * 4 + r;
        if (q < LSEQ)
          mix[(t0 + q) * C_DIM + h * 64 + c * 16 + fr] = (bf16_t)o4[c][r];
      }
  }
}

// -----------------------------------------------------------------------------
extern "C" void kernel_launch(void* const* d_in, const int* in_sizes, int n_in,
                              void* d_out, int out_size, void* d_ws,
                              size_t ws_size, hipStream_t stream) {
  const float* x = (const float*)d_in[0];
  const float* Wq = (const float*)d_in[1];
  const float* bq = (const float*)d_in[2];
  const float* Wk = (const float*)d_in[3];
  const float* bk = (const float*)d_in[4];
  const float* Wv = (const float*)d_in[5];
  const float* bv = (const float*)d_in[6];
  const float* Wo = (const float*)d_in[7];
  const float* bo = (const float*)d_in[8];
  const float* W1 = (const float*)d_in[9];
  const float* b1 = (const float*)d_in[10];
  const float* W2 = (const float*)d_in[11];
  const float* b2 = (const float*)d_in[12];
  const float* g1 = (const float*)d_in[13];
  const float* be1 = (const float*)d_in[14];
  const float* g2 = (const float*)d_in[15];
  const float* be2 = (const float*)d_in[16];

  char* ws = (char*)d_ws;
  size_t off = 0;
  auto alloc = [&](size_t bytes) {
    char* p = ws + off;
    off += (bytes + 255) & ~(size_t)255;
    return p;
  };
  bf16_t* xn = (bf16_t*)alloc((size_t)T_TOK * 768 * 2);
  char* qm = alloc((size_t)T_TOK * 3072 * 2);  // qkv[2304] + mix[768]; reused as h
  bf16_t* qkv = (bf16_t*)qm;
  bf16_t* mixb = (bf16_t*)(qm + (size_t)T_TOK * 2304 * 2);
  bf16_t* h = (bf16_t*)qm;
  bf16_t* Wqkvt = (bf16_t*)alloc((size_t)2304 * 768 * 2);
  bf16_t* Wot = (bf16_t*)alloc((size_t)768 * 768 * 2);
  bf16_t* W1t = (bf16_t*)alloc((size_t)3072 * 768 * 2);
  bf16_t* W2t = (bf16_t*)alloc((size_t)768 * 3072 * 2);
  float* bqkv = (float*)alloc(2304 * 4);
  float* x2 = (float*)d_out;  // residual stream 2 lives in d_out

  dim3 tb(32, 8);
  wprep_k<<<6912, tb, 0, stream>>>(Wq, Wk, Wv, Wo, W1, W2, Wqkvt, Wot, W1t,
                                   W2t);
  cat3_k<<<9, 256, 0, stream>>>(bq, bk, bv, bqkv);

  ln_k<<<T_TOK / 4, 256, 0, stream>>>(x, g1, be1, xn);
  gemm_bt<0, 128, 192><<<dim3(2304 / 192, T_TOK / 128), 256, 0, stream>>>(
      xn, Wqkvt, bqkv, nullptr, qkv, 768, 2304);
  attn_k<<<128 * NH, 256, 0, stream>>>(qkv, mixb);
  gemm_bt<1, 128, 192><<<dim3(768 / 192, T_TOK / 128), 256, 0, stream>>>(
      mixb, Wot, bo, x, x2, 768, 768);
  ln_k<<<T_TOK / 4, 256, 0, stream>>>(x2, g2, be2, xn);
  gemm_bt<2, 128, 192><<<dim3(3072 / 192, T_TOK / 128), 256, 0, stream>>>(
      xn, W1t, b1, nullptr, h, 768, 3072);
  gemm_bt<1, 128, 192><<<dim3(768 / 192, T_TOK / 128), 256, 0, stream>>>(
      h, W2t, b2, x2, (float*)d_out, 3072, 768);
}

// Round 15
// 702.697 us; speedup vs baseline: 1.3796x; 1.3796x over previous
//
#include <hip/hip_runtime.h>
#include <hip/hip_bf16.h>

typedef __bf16 bf16_t;
typedef __bf16 bf16x8 __attribute__((ext_vector_type(8)));
typedef float f32x4 __attribute__((ext_vector_type(4)));

#define T_TOK 25216
#define C_DIM 768
#define NH 12
#define LSEQ 197

__device__ __forceinline__ void gload_lds16(const bf16_t* g, bf16_t* l) {
  __builtin_amdgcn_global_load_lds(
      (const __attribute__((address_space(1))) unsigned int*)g,
      (__attribute__((address_space(3))) unsigned int*)l, 16, 0, 0);
}

template <int N>
__device__ __forceinline__ void vm_wait() {
  asm volatile("s_waitcnt vmcnt(%0)" ::"n"(N) : "memory");
}
__device__ __forceinline__ void block_bar() {
  __builtin_amdgcn_sched_barrier(0);
  asm volatile("" ::: "memory");
  __builtin_amdgcn_s_barrier();
  __builtin_amdgcn_sched_barrier(0);
}

// -------- merged weight prep: all transposes + bias concat, one launch -------
__device__ __forceinline__ void wtrans_body(const float* __restrict__ W,
                                            bf16_t* __restrict__ Wt, int K,
                                            int N, int bx, int by) {
  __shared__ float tile[32][33];
  const int tx = threadIdx.x, ty = threadIdx.y;
#pragma unroll
  for (int i = ty; i < 32; i += 8)
    tile[i][tx] = W[(long)(by * 32 + i) * N + bx * 32 + tx];
  __syncthreads();
#pragma unroll
  for (int i = ty; i < 32; i += 8)
    Wt[(long)(bx * 32 + i) * K + by * 32 + tx] = (bf16_t)tile[tx][i];
}

__global__ void wprep_k(const float* __restrict__ Wq,
                        const float* __restrict__ Wk,
                        const float* __restrict__ Wv,
                        const float* __restrict__ Wo,
                        const float* __restrict__ W1,
                        const float* __restrict__ W2,
                        const float* __restrict__ bq,
                        const float* __restrict__ bk,
                        const float* __restrict__ bv,
                        bf16_t* __restrict__ Wqkvt, bf16_t* __restrict__ Wot,
                        bf16_t* __restrict__ W1t, bf16_t* __restrict__ W2t,
                        float* __restrict__ bqkv) {
  const int b = blockIdx.x;
  if (b < 2304) {  // 4x 768x768 (24x24 each)
    const int z = b / 576, r = b % 576;
    const float* W = z == 0 ? Wq : (z == 1 ? Wk : (z == 2 ? Wv : Wo));
    bf16_t* Wt = z == 3 ? Wot : Wqkvt + (size_t)z * 768 * 768;
    wtrans_body(W, Wt, 768, 768, r % 24, r / 24);
  } else if (b < 4608) {  // W1: K=768, N=3072 (96x24)
    const int r = b - 2304;
    wtrans_body(W1, W1t, 768, 3072, r % 96, r / 96);
  } else if (b < 6912) {  // W2: K=3072, N=768 (24x96)
    const int r = b - 4608;
    wtrans_body(W2, W2t, 3072, 768, r % 24, r / 24);
  } else {  // bias concat: 2304 floats with 256 threads
    const int t = threadIdx.y * 32 + threadIdx.x;
#pragma unroll
    for (int i = 0; i < 9; ++i) {
      const int j = i * 256 + t;
      bqkv[j] = j < 768 ? bq[j] : (j < 1536 ? bk[j - 768] : bv[j - 1536]);
    }
  }
}

// ---------------- LayerNorm fp32 -> bf16, one wave per row -------------------
__global__ __launch_bounds__(256) void ln_k(const float* __restrict__ x,
                                            const float* __restrict__ g,
                                            const float* __restrict__ b,
                                            bf16_t* __restrict__ o) {
  const int lane = threadIdx.x & 63;
  const long row = (long)blockIdx.x * 4 + (threadIdx.x >> 6);
  const float* xr = x + row * C_DIM;
  float4 v[3];
  float s = 0.f, sq = 0.f;
#pragma unroll
  for (int i = 0; i < 3; ++i) {
    v[i] = *(const float4*)&xr[i * 256 + lane * 4];
    s += v[i].x + v[i].y + v[i].z + v[i].w;
    sq += v[i].x * v[i].x + v[i].y * v[i].y + v[i].z * v[i].z + v[i].w * v[i].w;
  }
#pragma unroll
  for (int off = 32; off; off >>= 1) {
    s += __shfl_xor(s, off);
    sq += __shfl_xor(sq, off);
  }
  const float mu = s * (1.f / 768.f);
  const float rstd = rsqrtf(sq * (1.f / 768.f) - mu * mu + 1e-5f);
  bf16_t* orow = o + row * C_DIM;
#pragma unroll
  for (int i = 0; i < 3; ++i) {
    const int c = i * 256 + lane * 4;
    const float4 gg = *(const float4*)&g[c];
    const float4 bb = *(const float4*)&b[c];
    bf16_t t4[4];
    t4[0] = (bf16_t)((v[i].x - mu) * rstd * gg.x + bb.x);
    t4[1] = (bf16_t)((v[i].y - mu) * rstd * gg.y + bb.y);
    t4[2] = (bf16_t)((v[i].z - mu) * rstd * gg.z + bb.z);
    t4[3] = (bf16_t)((v[i].w - mu) * rstd * gg.w + bb.w);
    __builtin_memcpy(&orow[c], t4, 8);
  }
}

// ---------------- GEMM: C[M,N] = A[M,K] @ Bt[N,K]^T + bias (+res) ------------
// Final configuration (verified best, R8/R13): 128x128 tile, BK=64, 4 waves.
// T1 XCD swizzle + T2 LDS XOR-swizzle (linear LDS dest via global_load_lds,
// inverse-swizzled global source, matching XOR on ds_read; 0 conflicts
// verified) + T4 counted vmcnt ping-pong (no drain in main loop).
// EPI 0: bf16 out (bias). EPI 1: f32 out (bias + res). EPI 2: bf16 QuickGELU.
template <int EPI, int BM, int BN>
__global__ __launch_bounds__(256) void gemm_bt(
    const bf16_t* __restrict__ A, const bf16_t* __restrict__ Bt,
    const float* __restrict__ bias, const float* __restrict__ res,
    void* __restrict__ outp, int K, int N) {
  constexpr int MACC = BM / 32;  // per-wave 16x16 frags in M (wave owns BM/2)
  constexpr int NACC = BN / 32;  // per-wave 16x16 frags in N (wave owns BN/2)
  constexpr int ACW = BM / 32;   // A gload calls per wave (8 rows each)
  constexpr int BCW = BN / 32;   // B gload calls per wave
  constexpr int NLOADS = ACW + BCW;  // vmem ops per stage per wave
  __shared__ __align__(16) bf16_t lA[2][BM * 64];
  __shared__ __align__(16) bf16_t lB[2][BN * 64];
  const int tid = threadIdx.x;
  const int wave = tid >> 6, lane = tid & 63;
  const int fr = lane & 15, fq = lane >> 4;

  // bijective XCD-chunked swizzle (m204): hw id -> contiguous per-XCD chunks
  const int gx = gridDim.x;
  const int nwg = gridDim.x * gridDim.y;
  int bid = blockIdx.y * gx + blockIdx.x;
  {
    const int q = nwg >> 3, r = nwg & 7;
    const int xcd = bid & 7, idx = bid >> 3;
    bid = (xcd < r ? xcd * (q + 1) : r * (q + 1) + (xcd - r) * q) + idx;
  }
  const int bx = bid % gx, by = bid / gx;

  const long rowBase = (long)by * BM;
  const long colBase = (long)bx * BN;
  const int wr = (wave >> 1) * (BM / 2), wc = (wave & 1) * (BN / 2);

  f32x4 acc[MACC][NACC];
#pragma unroll
  for (int m = 0; m < MACC; ++m)
#pragma unroll
    for (int n = 0; n < NACC; ++n) acc[m][n] = (f32x4){0.f, 0.f, 0.f, 0.f};

  const int srow = lane >> 3;  // 0..7
  // inverse-swizzled global source chunk: LDS slot (srow, lane&7) receives
  // global chunk (lane&7)^srow, so LDS[row][c] = global[row][c ^ (row&7)].
  const int scol = (((lane & 7) ^ srow)) * 8;  // elems

  // per-thread staging base pointers (advance by koff elems per K-step)
  const bf16_t* aP[ACW];
  const bf16_t* bP[BCW];
#pragma unroll
  for (int c = 0; c < ACW; ++c)
    aP[c] = A + (rowBase + 8 * (wave * ACW + c) + srow) * (long)K + scol;
#pragma unroll
  for (int c = 0; c < BCW; ++c)
    bP[c] = Bt + (colBase + 8 * (wave * BCW + c) + srow) * (long)K + scol;

  auto stage0 = [&](int koff) {
#pragma unroll
    for (int c = 0; c < ACW; ++c)
      gload_lds16(aP[c] + koff, &lA[0][(wave * ACW + c) * 512]);
#pragma unroll
    for (int c = 0; c < BCW; ++c)
      gload_lds16(bP[c] + koff, &lB[0][(wave * BCW + c) * 512]);
  };
  auto stage1 = [&](int koff) {
#pragma unroll
    for (int c = 0; c < ACW; ++c)
      gload_lds16(aP[c] + koff, &lA[1][(wave * ACW + c) * 512]);
#pragma unroll
    for (int c = 0; c < BCW; ++c)
      gload_lds16(bP[c] + koff, &lB[1][(wave * BCW + c) * 512]);
  };
  auto compute0 = [&]() {
#pragma unroll
    for (int kf = 0; kf < 2; ++kf) {
      bf16x8 af[MACC], bfr[NACC];
#pragma unroll
      for (int m = 0; m < MACC; ++m) {
        const int row = wr + m * 16 + fr;
        af[m] =
            *(const bf16x8*)&lA[0][row * 64 + (((kf * 4 + fq) ^ (fr & 7)) * 8)];
      }
#pragma unroll
      for (int n = 0; n < NACC; ++n) {
        const int row = wc + n * 16 + fr;
        bfr[n] =
            *(const bf16x8*)&lB[0][row * 64 + (((kf * 4 + fq) ^ (fr & 7)) * 8)];
      }
#pragma unroll
      for (int m = 0; m < MACC; ++m)
#pragma unroll
        for (int n = 0; n < NACC; ++n)
          acc[m][n] = __builtin_amdgcn_mfma_f32_16x16x32_bf16(af[m], bfr[n],
                                                              acc[m][n], 0, 0, 0);
    }
  };
  auto compute1 = [&]() {
#pragma unroll
    for (int kf = 0; kf < 2; ++kf) {
      bf16x8 af[MACC], bfr[NACC];
#pragma unroll
      for (int m = 0; m < MACC; ++m) {
        const int row = wr + m * 16 + fr;
        af[m] =
            *(const bf16x8*)&lA[1][row * 64 + (((kf * 4 + fq) ^ (fr & 7)) * 8)];
      }
#pragma unroll
      for (int n = 0; n < NACC; ++n) {
        const int row = wc + n * 16 + fr;
        bfr[n] =
            *(const bf16x8*)&lB[1][row * 64 + (((kf * 4 + fq) ^ (fr & 7)) * 8)];
      }
#pragma unroll
      for (int m = 0; m < MACC; ++m)
#pragma unroll
        for (int n = 0; n < NACC; ++n)
          acc[m][n] = __builtin_amdgcn_mfma_f32_16x16x32_bf16(af[m], bfr[n],
                                                              acc[m][n], 0, 0, 0);
    }
  };

  const int kT = K >> 6;  // 12 or 48 (even)
  stage0(0);
  // main loop: buf0 holds tile kt, buf1 gets kt+1; counted vmcnt, no drain.
  int kt = 0;
  for (; kt + 2 < kT; kt += 2) {
    stage1((kt + 1) * 64);   // prefetch kt+1 (in flight across barriers)
    vm_wait<NLOADS>();       // my tile-kt loads done (prefetch outstanding)
    block_bar();             // => ALL waves' tile-kt loads done
    compute0();
    block_bar();             // buf0 reads done everywhere -> safe to overwrite
    stage0((kt + 2) * 64);   // prefetch kt+2
    vm_wait<NLOADS>();       // tile-(kt+1) loads done
    block_bar();
    compute1();
    block_bar();             // buf1 reads done -> next iter may overwrite
  }
  // tail: kt == kT-2; buf0 holds kT-2
  stage1((kt + 1) * 64);
  vm_wait<NLOADS>();
  block_bar();
  compute0();
  vm_wait<0>();  // drain last prefetch (only remaining vmem)
  block_bar();
  compute1();

#pragma unroll
  for (int m = 0; m < MACC; ++m) {
    const long row0 = rowBase + wr + m * 16 + fq * 4;
#pragma unroll
    for (int n = 0; n < NACC; ++n) {
      const long col = colBase + wc + n * 16 + fr;
      const float bb = bias[col];
#pragma unroll
      for (int r = 0; r < 4; ++r) {
        const long idx = (row0 + r) * N + col;
        float v = acc[m][n][r] + bb;
        if (EPI == 0) {
          ((bf16_t*)outp)[idx] = (bf16_t)v;
        } else if (EPI == 1) {
          ((float*)outp)[idx] = v + res[idx];
        } else {
          v = v / (1.f + __expf(-1.702f * v));
          ((bf16_t*)outp)[idx] = (bf16_t)v;
        }
      }
    }
  }
}

// ---------------- attention: one block per (batch, head) ---------------------
// qkv [T][2304] bf16 (q|k|v per token). mix [T][768] bf16 output.
__global__ __launch_bounds__(256) void attn_k(const bf16_t* __restrict__ qkv,
                                              bf16_t* __restrict__ mix) {
  constexpr int KR = 72;   // lK row stride (elems): 144B -> 2-way banks, 16B aligned
  constexpr int VR = 232;  // lVt/lP row stride: 464B -> 2-way banks, 16B aligned
  __shared__ __align__(16) bf16_t smem[208 * KR + 64 * VR + 64 * VR];
  bf16_t* lK = smem;
  bf16_t* lVt = smem + 208 * KR;
  bf16_t* lP = lVt + 64 * VR;

  const int tid = threadIdx.x;
  const int wave = tid >> 6, lane = tid & 63;
  const int fr = lane & 15, fq = lane >> 4;
  const int nh = blockIdx.x;
  const int n = nh / NH, h = nh % NH;
  const long t0 = (long)n * LSEQ;
  const long qs = 2304;

  {  // zero all LDS (covers K rows >=197, V cols >=197, P cols >= 208)
    int4 z = {0, 0, 0, 0};
    int4* p = (int4*)smem;
    const int tot = (208 * KR + 2 * 64 * VR) * 2 / 16;
    for (int i = tid; i < tot; i += 256) p[i] = z;
  }
  __syncthreads();

  for (int it = tid; it < 197 * 8; it += 256) {  // K rows
    int r = it >> 3, cg = it & 7;
    int4 v = *(const int4*)(qkv + (t0 + r) * qs + 768 + h * 64 + cg * 8);
    *(int4*)&lK[r * KR + cg * 8] = v;
  }
  for (int it = tid; it < 197 * 8; it += 256) {  // V transpose
    int r = it >> 3, cg = it & 7;
    int4 v = *(const int4*)(qkv + (t0 + r) * qs + 1536 + h * 64 + cg * 8);
    const bf16_t* pv = (const bf16_t*)&v;
#pragma unroll
    for (int j = 0; j < 8; ++j) lVt[(cg * 8 + j) * VR + r] = pv[j];
  }
  __syncthreads();

  bf16_t* lPw = lP + wave * 16 * VR;

  for (int fi = 0; fi < 4; ++fi) {
    const int f = wave + fi * 4;
    if (f >= 13) break;
    const int qrow = f * 16 + fr;
    const long tq = t0 + (qrow < LSEQ ? qrow : LSEQ - 1);
    const bf16_t* qp = qkv + tq * qs + h * 64;
    bf16x8 a0 = *(const bf16x8*)(qp + fq * 8);
    bf16x8 a1 = *(const bf16x8*)(qp + 32 + fq * 8);

    f32x4 s[13];
#pragma unroll
    for (int j = 0; j < 13; ++j) s[j] = (f32x4){0.f, 0.f, 0.f, 0.f};
#pragma unroll
    for (int j = 0; j < 13; ++j) {
      bf16x8 b0 = *(const bf16x8*)&lK[(j * 16 + fr) * KR + fq * 8];
      s[j] = __builtin_amdgcn_mfma_f32_16x16x32_bf16(a0, b0, s[j], 0, 0, 0);
      bf16x8 b1 = *(const bf16x8*)&lK[(j * 16 + fr) * KR + 32 + fq * 8];
      s[j] = __builtin_amdgcn_mfma_f32_16x16x32_bf16(a1, b1, s[j], 0, 0, 0);
    }
    // wave-parallel softmax over keys (row = fq*4+r, key = j*16 + lane&15)
    float mx[4] = {-3e38f, -3e38f, -3e38f, -3e38f};
#pragma unroll
    for (int j = 0; j < 13; ++j) {
      const bool valid = (j * 16 + fr) < LSEQ;
#pragma unroll
      for (int r = 0; r < 4; ++r) {
        float v = s[j][r] * 0.125f;
        v = valid ? v : -3e38f;
        s[j][r] = v;
        mx[r] = fmaxf(mx[r], v);
      }
    }
#pragma unroll
    for (int r = 0; r < 4; ++r) {
      mx[r] = fmaxf(mx[r], __shfl_xor(mx[r], 1));
      mx[r] = fmaxf(mx[r], __shfl_xor(mx[r], 2));
      mx[r] = fmaxf(mx[r], __shfl_xor(mx[r], 4));
      mx[r] = fmaxf(mx[r], __shfl_xor(mx[r], 8));
    }
    float sm[4] = {0.f, 0.f, 0.f, 0.f};
#pragma unroll
    for (int j = 0; j < 13; ++j)
#pragma unroll
      for (int r = 0; r < 4; ++r) {
        float e = __expf(s[j][r] - mx[r]);
        s[j][r] = e;
        sm[r] += e;
      }
#pragma unroll
    for (int r = 0; r < 4; ++r) {
      sm[r] += __shfl_xor(sm[r], 1);
      sm[r] += __shfl_xor(sm[r], 2);
      sm[r] += __shfl_xor(sm[r], 4);
      sm[r] += __shfl_xor(sm[r], 8);
      sm[r] = 1.f / sm[r];
    }
#pragma unroll
    for (int j = 0; j < 13; ++j)
#pragma unroll
      for (int r = 0; r < 4; ++r)
        lPw[(fq * 4 + r) * VR + j * 16 + fr] = (bf16_t)(s[j][r] * sm[r]);
    asm volatile("s_waitcnt lgkmcnt(0)" ::: "memory");

    f32x4 o4[4];
#pragma unroll
    for (int c = 0; c < 4; ++c) o4[c] = (f32x4){0.f, 0.f, 0.f, 0.f};
#pragma unroll
    for (int kc = 0; kc < 7; ++kc) {
      bf16x8 pa = *(const bf16x8*)&lPw[fr * VR + kc * 32 + fq * 8];
#pragma unroll
      for (int c = 0; c < 4; ++c) {
        bf16x8 bv = *(const bf16x8*)&lVt[(c * 16 + fr) * VR + kc * 32 + fq * 8];
        o4[c] = __builtin_amdgcn_mfma_f32_16x16x32_bf16(pa, bv, o4[c], 0, 0, 0);
      }
    }
#pragma unroll
    for (int c = 0; c < 4; ++c)
#pragma unroll
      for (int r = 0; r < 4; ++r) {
        const int q = f * 16 + fq * 4 + r;
        if (q < LSEQ)
          mix[(t0 + q) * C_DIM + h * 64 + c * 16 + fr] = (bf16_t)o4[c][r];
      }
  }
}

// -----------------------------------------------------------------------------
extern "C" void kernel_launch(void* const* d_in, const int* in_sizes, int n_in,
                              void* d_out, int out_size, void* d_ws,
                              size_t ws_size, hipStream_t stream) {
  const float* x = (const float*)d_in[0];
  const float* Wq = (const float*)d_in[1];
  const float* bq = (const float*)d_in[2];
  const float* Wk = (const float*)d_in[3];
  const float* bk = (const float*)d_in[4];
  const float* Wv = (const float*)d_in[5];
  const float* bv = (const float*)d_in[6];
  const float* Wo = (const float*)d_in[7];
  const float* bo = (const float*)d_in[8];
  const float* W1 = (const float*)d_in[9];
  const float* b1 = (const float*)d_in[10];
  const float* W2 = (const float*)d_in[11];
  const float* b2 = (const float*)d_in[12];
  const float* g1 = (const float*)d_in[13];
  const float* be1 = (const float*)d_in[14];
  const float* g2 = (const float*)d_in[15];
  const float* be2 = (const float*)d_in[16];

  char* ws = (char*)d_ws;
  size_t off = 0;
  auto alloc = [&](size_t bytes) {
    char* p = ws + off;
    off += (bytes + 255) & ~(size_t)255;
    return p;
  };
  bf16_t* xn = (bf16_t*)alloc((size_t)T_TOK * 768 * 2);
  char* qm = alloc((size_t)T_TOK * 3072 * 2);  // qkv[2304] + mix[768]; reused as h
  bf16_t* qkv = (bf16_t*)qm;
  bf16_t* mixb = (bf16_t*)(qm + (size_t)T_TOK * 2304 * 2);
  bf16_t* h = (bf16_t*)qm;
  bf16_t* Wqkvt = (bf16_t*)alloc((size_t)2304 * 768 * 2);
  bf16_t* Wot = (bf16_t*)alloc((size_t)768 * 768 * 2);
  bf16_t* W1t = (bf16_t*)alloc((size_t)3072 * 768 * 2);
  bf16_t* W2t = (bf16_t*)alloc((size_t)768 * 3072 * 2);
  float* bqkv = (float*)alloc(2304 * 4);
  float* x2 = (float*)d_out;  // residual stream 2 lives in d_out

  dim3 tb(32, 8);
  wprep_k<<<6913, tb, 0, stream>>>(Wq, Wk, Wv, Wo, W1, W2, bq, bk, bv, Wqkvt,
                                   Wot, W1t, W2t, bqkv);

  ln_k<<<T_TOK / 4, 256, 0, stream>>>(x, g1, be1, xn);
  gemm_bt<0, 128, 128><<<dim3(2304 / 128, T_TOK / 128), 256, 0, stream>>>(
      xn, Wqkvt, bqkv, nullptr, qkv, 768, 2304);
  attn_k<<<128 * NH, 256, 0, stream>>>(qkv, mixb);
  gemm_bt<1, 128, 128><<<dim3(768 / 128, T_TOK / 128), 256, 0, stream>>>(
      mixb, Wot, bo, x, x2, 768, 768);
  ln_k<<<T_TOK / 4, 256, 0, stream>>>(x2, g2, be2, xn);
  gemm_bt<2, 128, 128><<<dim3(3072 / 128, T_TOK / 128), 256, 0, stream>>>(
      xn, W1t, b1, nullptr, h, 768, 3072);
  gemm_bt<1, 128, 128><<<dim3(768 / 128, T_TOK / 128), 256, 0, stream>>>(
      h, W2t, b2, x2, (float*)d_out, 3072, 768);
}

// Round 16
// 693.388 us; speedup vs baseline: 1.3981x; 1.0134x over previous
//
#include <hip/hip_runtime.h>
#include <hip/hip_bf16.h>

typedef __bf16 bf16_t;
typedef __bf16 bf16x8 __attribute__((ext_vector_type(8)));
typedef float f32x4 __attribute__((ext_vector_type(4)));

#define T_TOK 25216
#define C_DIM 768
#define NH 12
#define LSEQ 197

__device__ __forceinline__ void gload_lds16(const bf16_t* g, bf16_t* l) {
  __builtin_amdgcn_global_load_lds(
      (const __attribute__((address_space(1))) unsigned int*)g,
      (__attribute__((address_space(3))) unsigned int*)l, 16, 0, 0);
}

template <int N>
__device__ __forceinline__ void vm_wait() {
  asm volatile("s_waitcnt vmcnt(%0)" ::"n"(N) : "memory");
}
__device__ __forceinline__ void block_bar() {
  __builtin_amdgcn_sched_barrier(0);
  asm volatile("" ::: "memory");
  __builtin_amdgcn_s_barrier();
  __builtin_amdgcn_sched_barrier(0);
}

// -------- merged weight prep: all transposes + bias concat, one launch -------
__device__ __forceinline__ void wtrans_body(const float* __restrict__ W,
                                            bf16_t* __restrict__ Wt, int K,
                                            int N, int bx, int by) {
  __shared__ float tile[32][33];
  const int tx = threadIdx.x, ty = threadIdx.y;
#pragma unroll
  for (int i = ty; i < 32; i += 8)
    tile[i][tx] = W[(long)(by * 32 + i) * N + bx * 32 + tx];
  __syncthreads();
#pragma unroll
  for (int i = ty; i < 32; i += 8)
    Wt[(long)(bx * 32 + i) * K + by * 32 + tx] = (bf16_t)tile[tx][i];
}

__global__ void wprep_k(const float* __restrict__ Wq,
                        const float* __restrict__ Wk,
                        const float* __restrict__ Wv,
                        const float* __restrict__ Wo,
                        const float* __restrict__ W1,
                        const float* __restrict__ W2,
                        const float* __restrict__ bq,
                        const float* __restrict__ bk,
                        const float* __restrict__ bv,
                        bf16_t* __restrict__ Wqkvt, bf16_t* __restrict__ Wot,
                        bf16_t* __restrict__ W1t, bf16_t* __restrict__ W2t,
                        float* __restrict__ bqkv) {
  const int b = blockIdx.x;
  if (b < 2304) {  // 4x 768x768 (24x24 each)
    const int z = b / 576, r = b % 576;
    const float* W = z == 0 ? Wq : (z == 1 ? Wk : (z == 2 ? Wv : Wo));
    bf16_t* Wt = z == 3 ? Wot : Wqkvt + (size_t)z * 768 * 768;
    wtrans_body(W, Wt, 768, 768, r % 24, r / 24);
  } else if (b < 4608) {  // W1: K=768, N=3072 (96x24)
    const int r = b - 2304;
    wtrans_body(W1, W1t, 768, 3072, r % 96, r / 96);
  } else if (b < 6912) {  // W2: K=3072, N=768 (24x96)
    const int r = b - 4608;
    wtrans_body(W2, W2t, 3072, 768, r % 24, r / 24);
  } else {  // bias concat: 2304 floats with 256 threads
    const int t = threadIdx.y * 32 + threadIdx.x;
#pragma unroll
    for (int i = 0; i < 9; ++i) {
      const int j = i * 256 + t;
      bqkv[j] = j < 768 ? bq[j] : (j < 1536 ? bk[j - 768] : bv[j - 1536]);
    }
  }
}

// -------- LayerNorm -> bf16, one wave per row; BIN=0 f32 in, BIN=1 bf16 in ---
template <int BIN>
__global__ __launch_bounds__(256) void ln_k(const void* __restrict__ xv,
                                            const float* __restrict__ g,
                                            const float* __restrict__ b,
                                            bf16_t* __restrict__ o) {
  const int lane = threadIdx.x & 63;
  const long row = (long)blockIdx.x * 4 + (threadIdx.x >> 6);
  float4 v[3];
  if (BIN == 0) {
    const float* xr = (const float*)xv + row * C_DIM;
#pragma unroll
    for (int i = 0; i < 3; ++i) v[i] = *(const float4*)&xr[i * 256 + lane * 4];
  } else {
    const bf16_t* xr = (const bf16_t*)xv + row * C_DIM;
#pragma unroll
    for (int i = 0; i < 3; ++i) {  // explicit 8B vector load (G13)
      ushort4 u = *(const ushort4*)&xr[i * 256 + lane * 4];
      v[i].x = __uint_as_float((unsigned)u.x << 16);
      v[i].y = __uint_as_float((unsigned)u.y << 16);
      v[i].z = __uint_as_float((unsigned)u.z << 16);
      v[i].w = __uint_as_float((unsigned)u.w << 16);
    }
  }
  float s = 0.f, sq = 0.f;
#pragma unroll
  for (int i = 0; i < 3; ++i) {
    s += v[i].x + v[i].y + v[i].z + v[i].w;
    sq += v[i].x * v[i].x + v[i].y * v[i].y + v[i].z * v[i].z + v[i].w * v[i].w;
  }
#pragma unroll
  for (int off = 32; off; off >>= 1) {
    s += __shfl_xor(s, off);
    sq += __shfl_xor(sq, off);
  }
  const float mu = s * (1.f / 768.f);
  const float rstd = rsqrtf(sq * (1.f / 768.f) - mu * mu + 1e-5f);
  bf16_t* orow = o + row * C_DIM;
#pragma unroll
  for (int i = 0; i < 3; ++i) {
    const int c = i * 256 + lane * 4;
    const float4 gg = *(const float4*)&g[c];
    const float4 bb = *(const float4*)&b[c];
    bf16_t t4[4];
    t4[0] = (bf16_t)((v[i].x - mu) * rstd * gg.x + bb.x);
    t4[1] = (bf16_t)((v[i].y - mu) * rstd * gg.y + bb.y);
    t4[2] = (bf16_t)((v[i].z - mu) * rstd * gg.z + bb.z);
    t4[3] = (bf16_t)((v[i].w - mu) * rstd * gg.w + bb.w);
    __builtin_memcpy(&orow[c], t4, 8);
  }
}

// ---------------- GEMM: C[M,N] = A[M,K] @ Bt[N,K]^T + bias (+res) ------------
// Final configuration (verified best, R8/R13/R15): 128x128 tile, BK=64,
// 4 waves. T1 XCD swizzle + T2 LDS XOR-swizzle (0 conflicts verified) + T4
// counted vmcnt ping-pong (no drain in main loop).
// EPI 0: bf16 out (bias).            EPI 1: f32 out (bias + f32 res).
// EPI 2: bf16 QuickGELU.             EPI 3: bf16 out (bias + f32 res).
// EPI 4: f32 out (bias + bf16 res).
template <int EPI, int BM, int BN>
__global__ __launch_bounds__(256) void gemm_bt(
    const bf16_t* __restrict__ A, const bf16_t* __restrict__ Bt,
    const float* __restrict__ bias, const void* __restrict__ resv,
    void* __restrict__ outp, int K, int N) {
  constexpr int MACC = BM / 32;  // per-wave 16x16 frags in M (wave owns BM/2)
  constexpr int NACC = BN / 32;  // per-wave 16x16 frags in N (wave owns BN/2)
  constexpr int ACW = BM / 32;   // A gload calls per wave (8 rows each)
  constexpr int BCW = BN / 32;   // B gload calls per wave
  constexpr int NLOADS = ACW + BCW;  // vmem ops per stage per wave
  __shared__ __align__(16) bf16_t lA[2][BM * 64];
  __shared__ __align__(16) bf16_t lB[2][BN * 64];
  const int tid = threadIdx.x;
  const int wave = tid >> 6, lane = tid & 63;
  const int fr = lane & 15, fq = lane >> 4;

  // bijective XCD-chunked swizzle (m204): hw id -> contiguous per-XCD chunks
  const int gx = gridDim.x;
  const int nwg = gridDim.x * gridDim.y;
  int bid = blockIdx.y * gx + blockIdx.x;
  {
    const int q = nwg >> 3, r = nwg & 7;
    const int xcd = bid & 7, idx = bid >> 3;
    bid = (xcd < r ? xcd * (q + 1) : r * (q + 1) + (xcd - r) * q) + idx;
  }
  const int bx = bid % gx, by = bid / gx;

  const long rowBase = (long)by * BM;
  const long colBase = (long)bx * BN;
  const int wr = (wave >> 1) * (BM / 2), wc = (wave & 1) * (BN / 2);

  f32x4 acc[MACC][NACC];
#pragma unroll
  for (int m = 0; m < MACC; ++m)
#pragma unroll
    for (int n = 0; n < NACC; ++n) acc[m][n] = (f32x4){0.f, 0.f, 0.f, 0.f};

  const int srow = lane >> 3;  // 0..7
  // inverse-swizzled global source chunk: LDS slot (srow, lane&7) receives
  // global chunk (lane&7)^srow, so LDS[row][c] = global[row][c ^ (row&7)].
  const int scol = (((lane & 7) ^ srow)) * 8;  // elems

  // per-thread staging base pointers (advance by koff elems per K-step)
  const bf16_t* aP[ACW];
  const bf16_t* bP[BCW];
#pragma unroll
  for (int c = 0; c < ACW; ++c)
    aP[c] = A + (rowBase + 8 * (wave * ACW + c) + srow) * (long)K + scol;
#pragma unroll
  for (int c = 0; c < BCW; ++c)
    bP[c] = Bt + (colBase + 8 * (wave * BCW + c) + srow) * (long)K + scol;

  auto stage0 = [&](int koff) {
#pragma unroll
    for (int c = 0; c < ACW; ++c)
      gload_lds16(aP[c] + koff, &lA[0][(wave * ACW + c) * 512]);
#pragma unroll
    for (int c = 0; c < BCW; ++c)
      gload_lds16(bP[c] + koff, &lB[0][(wave * BCW + c) * 512]);
  };
  auto stage1 = [&](int koff) {
#pragma unroll
    for (int c = 0; c < ACW; ++c)
      gload_lds16(aP[c] + koff, &lA[1][(wave * ACW + c) * 512]);
#pragma unroll
    for (int c = 0; c < BCW; ++c)
      gload_lds16(bP[c] + koff, &lB[1][(wave * BCW + c) * 512]);
  };
  auto compute0 = [&]() {
#pragma unroll
    for (int kf = 0; kf < 2; ++kf) {
      bf16x8 af[MACC], bfr[NACC];
#pragma unroll
      for (int m = 0; m < MACC; ++m) {
        const int row = wr + m * 16 + fr;
        af[m] =
            *(const bf16x8*)&lA[0][row * 64 + (((kf * 4 + fq) ^ (fr & 7)) * 8)];
      }
#pragma unroll
      for (int n = 0; n < NACC; ++n) {
        const int row = wc + n * 16 + fr;
        bfr[n] =
            *(const bf16x8*)&lB[0][row * 64 + (((kf * 4 + fq) ^ (fr & 7)) * 8)];
      }
#pragma unroll
      for (int m = 0; m < MACC; ++m)
#pragma unroll
        for (int n = 0; n < NACC; ++n)
          acc[m][n] = __builtin_amdgcn_mfma_f32_16x16x32_bf16(af[m], bfr[n],
                                                              acc[m][n], 0, 0, 0);
    }
  };
  auto compute1 = [&]() {
#pragma unroll
    for (int kf = 0; kf < 2; ++kf) {
      bf16x8 af[MACC], bfr[NACC];
#pragma unroll
      for (int m = 0; m < MACC; ++m) {
        const int row = wr + m * 16 + fr;
        af[m] =
            *(const bf16x8*)&lA[1][row * 64 + (((kf * 4 + fq) ^ (fr & 7)) * 8)];
      }
#pragma unroll
      for (int n = 0; n < NACC; ++n) {
        const int row = wc + n * 16 + fr;
        bfr[n] =
            *(const bf16x8*)&lB[1][row * 64 + (((kf * 4 + fq) ^ (fr & 7)) * 8)];
      }
#pragma unroll
      for (int m = 0; m < MACC; ++m)
#pragma unroll
        for (int n = 0; n < NACC; ++n)
          acc[m][n] = __builtin_amdgcn_mfma_f32_16x16x32_bf16(af[m], bfr[n],
                                                              acc[m][n], 0, 0, 0);
    }
  };

  const int kT = K >> 6;  // 12 or 48 (even)
  stage0(0);
  // main loop: buf0 holds tile kt, buf1 gets kt+1; counted vmcnt, no drain.
  int kt = 0;
  for (; kt + 2 < kT; kt += 2) {
    stage1((kt + 1) * 64);   // prefetch kt+1 (in flight across barriers)
    vm_wait<NLOADS>();       // my tile-kt loads done (prefetch outstanding)
    block_bar();             // => ALL waves' tile-kt loads done
    compute0();
    block_bar();             // buf0 reads done everywhere -> safe to overwrite
    stage0((kt + 2) * 64);   // prefetch kt+2
    vm_wait<NLOADS>();       // tile-(kt+1) loads done
    block_bar();
    compute1();
    block_bar();             // buf1 reads done -> next iter may overwrite
  }
  // tail: kt == kT-2; buf0 holds kT-2
  stage1((kt + 1) * 64);
  vm_wait<NLOADS>();
  block_bar();
  compute0();
  vm_wait<0>();  // drain last prefetch (only remaining vmem)
  block_bar();
  compute1();

#pragma unroll
  for (int m = 0; m < MACC; ++m) {
    const long row0 = rowBase + wr + m * 16 + fq * 4;
#pragma unroll
    for (int n = 0; n < NACC; ++n) {
      const long col = colBase + wc + n * 16 + fr;
      const float bb = bias[col];
#pragma unroll
      for (int r = 0; r < 4; ++r) {
        const long idx = (row0 + r) * N + col;
        float v = acc[m][n][r] + bb;
        if (EPI == 0) {
          ((bf16_t*)outp)[idx] = (bf16_t)v;
        } else if (EPI == 1) {
          ((float*)outp)[idx] = v + ((const float*)resv)[idx];
        } else if (EPI == 2) {
          v = v / (1.f + __expf(-1.702f * v));
          ((bf16_t*)outp)[idx] = (bf16_t)v;
        } else if (EPI == 3) {
          ((bf16_t*)outp)[idx] = (bf16_t)(v + ((const float*)resv)[idx]);
        } else {  // EPI == 4
          ((float*)outp)[idx] = v + (float)((const bf16_t*)resv)[idx];
        }
      }
    }
  }
}

// ---------------- attention: one block per (batch, head) ---------------------
// qkv [T][2304] bf16 (q|k|v per token). mix [T][768] bf16 output.
__global__ __launch_bounds__(256) void attn_k(const bf16_t* __restrict__ qkv,
                                              bf16_t* __restrict__ mix) {
  constexpr int KR = 72;   // lK row stride (elems): 144B -> 2-way banks, 16B aligned
  constexpr int VR = 232;  // lVt/lP row stride: 464B -> 2-way banks, 16B aligned
  __shared__ __align__(16) bf16_t smem[208 * KR + 64 * VR + 64 * VR];
  bf16_t* lK = smem;
  bf16_t* lVt = smem + 208 * KR;
  bf16_t* lP = lVt + 64 * VR;

  const int tid = threadIdx.x;
  const int wave = tid >> 6, lane = tid & 63;
  const int fr = lane & 15, fq = lane >> 4;
  const int nh = blockIdx.x;
  const int n = nh / NH, h = nh % NH;
  const long t0 = (long)n * LSEQ;
  const long qs = 2304;

  {  // zero lVt + lP only. lK needs no zeroing: pad rows (>=197) feed the QK^T
     // MFMA but the resulting s values are replaced via the `valid` cndmask
     // (NaN-safe). lVt pad cols / lP cols >=208 ARE read by PV and must be 0.
    int4 z = {0, 0, 0, 0};
    int4* p = (int4*)lVt;
    const int tot = (2 * 64 * VR) * 2 / 16;
    for (int i = tid; i < tot; i += 256) p[i] = z;
  }
  __syncthreads();

  for (int it = tid; it < 197 * 8; it += 256) {  // K rows
    int r = it >> 3, cg = it & 7;
    int4 v = *(const int4*)(qkv + (t0 + r) * qs + 768 + h * 64 + cg * 8);
    *(int4*)&lK[r * KR + cg * 8] = v;
  }
  for (int it = tid; it < 197 * 8; it += 256) {  // V transpose
    int r = it >> 3, cg = it & 7;
    int4 v = *(const int4*)(qkv + (t0 + r) * qs + 1536 + h * 64 + cg * 8);
    const bf16_t* pv = (const bf16_t*)&v;
#pragma unroll
    for (int j = 0; j < 8; ++j) lVt[(cg * 8 + j) * VR + r] = pv[j];
  }
  __syncthreads();

  bf16_t* lPw = lP + wave * 16 * VR;

  for (int fi = 0; fi < 4; ++fi) {
    const int f = wave + fi * 4;
    if (f >= 13) break;
    const int qrow = f * 16 + fr;
    const long tq = t0 + (qrow < LSEQ ? qrow : LSEQ - 1);
    const bf16_t* qp = qkv + tq * qs + h * 64;
    bf16x8 a0 = *(const bf16x8*)(qp + fq * 8);
    bf16x8 a1 = *(const bf16x8*)(qp + 32 + fq * 8);

    f32x4 s[13];
#pragma unroll
    for (int j = 0; j < 13; ++j) s[j] = (f32x4){0.f, 0.f, 0.f, 0.f};
#pragma unroll
    for (int j = 0; j < 13; ++j) {
      bf16x8 b0 = *(const bf16x8*)&lK[(j * 16 + fr) * KR + fq * 8];
      s[j] = __builtin_amdgcn_mfma_f32_16x16x32_bf16(a0, b0, s[j], 0, 0, 0);
      bf16x8 b1 = *(const bf16x8*)&lK[(j * 16 + fr) * KR + 32 + fq * 8];
      s[j] = __builtin_amdgcn_mfma_f32_16x16x32_bf16(a1, b1, s[j], 0, 0, 0);
    }
    // wave-parallel softmax over keys (row = fq*4+r, key = j*16 + lane&15)
    float mx[4] = {-3e38f, -3e38f, -3e38f, -3e38f};
#pragma unroll
    for (int j = 0; j < 13; ++j) {
      const bool valid = (j * 16 + fr) < LSEQ;
#pragma unroll
      for (int r = 0; r < 4; ++r) {
        float v = s[j][r] * 0.125f;
        v = valid ? v : -3e38f;
        s[j][r] = v;
        mx[r] = fmaxf(mx[r], v);
      }
    }
#pragma unroll
    for (int r = 0; r < 4; ++r) {
      mx[r] = fmaxf(mx[r], __shfl_xor(mx[r], 1));
      mx[r] = fmaxf(mx[r], __shfl_xor(mx[r], 2));
      mx[r] = fmaxf(mx[r], __shfl_xor(mx[r], 4));
      mx[r] = fmaxf(mx[r], __shfl_xor(mx[r], 8));
    }
    float sm[4] = {0.f, 0.f, 0.f, 0.f};
#pragma unroll
    for (int j = 0; j < 13; ++j)
#pragma unroll
      for (int r = 0; r < 4; ++r) {
        float e = __expf(s[j][r] - mx[r]);
        s[j][r] = e;
        sm[r] += e;
      }
#pragma unroll
    for (int r = 0; r < 4; ++r) {
      sm[r] += __shfl_xor(sm[r], 1);
      sm[r] += __shfl_xor(sm[r], 2);
      sm[r] += __shfl_xor(sm[r], 4);
      sm[r] += __shfl_xor(sm[r], 8);
      sm[r] = 1.f / sm[r];
    }
#pragma unroll
    for (int j = 0; j < 13; ++j)
#pragma unroll
      for (int r = 0; r < 4; ++r)
        lPw[(fq * 4 + r) * VR + j * 16 + fr] = (bf16_t)(s[j][r] * sm[r]);
    asm volatile("s_waitcnt lgkmcnt(0)" ::: "memory");

    f32x4 o4[4];
#pragma unroll
    for (int c = 0; c < 4; ++c) o4[c] = (f32x4){0.f, 0.f, 0.f, 0.f};
#pragma unroll
    for (int kc = 0; kc < 7; ++kc) {
      bf16x8 pa = *(const bf16x8*)&lPw[fr * VR + kc * 32 + fq * 8];
#pragma unroll
      for (int c = 0; c < 4; ++c) {
        bf16x8 bv = *(const bf16x8*)&lVt[(c * 16 + fr) * VR + kc * 32 + fq * 8];
        o4[c] = __builtin_amdgcn_mfma_f32_16x16x32_bf16(pa, bv, o4[c], 0, 0, 0);
      }
    }
#pragma unroll
    for (int c = 0; c < 4; ++c)
#pragma unroll
      for (int r = 0; r < 4; ++r) {
        const int q = f * 16 + fq * 4 + r;
        if (q < LSEQ)
          mix[(t0 + q) * C_DIM + h * 64 + c * 16 + fr] = (bf16_t)o4[c][r];
      }
  }
}

// -----------------------------------------------------------------------------
extern "C" void kernel_launch(void* const* d_in, const int* in_sizes, int n_in,
                              void* d_out, int out_size, void* d_ws,
                              size_t ws_size, hipStream_t stream) {
  const float* x = (const float*)d_in[0];
  const float* Wq = (const float*)d_in[1];
  const float* bq = (const float*)d_in[2];
  const float* Wk = (const float*)d_in[3];
  const float* bk = (const float*)d_in[4];
  const float* Wv = (const float*)d_in[5];
  const float* bv = (const float*)d_in[6];
  const float* Wo = (const float*)d_in[7];
  const float* bo = (const float*)d_in[8];
  const float* W1 = (const float*)d_in[9];
  const float* b1 = (const float*)d_in[10];
  const float* W2 = (const float*)d_in[11];
  const float* b2 = (const float*)d_in[12];
  const float* g1 = (const float*)d_in[13];
  const float* be1 = (const float*)d_in[14];
  const float* g2 = (const float*)d_in[15];
  const float* be2 = (const float*)d_in[16];

  char* ws = (char*)d_ws;
  size_t off = 0;
  auto alloc = [&](size_t bytes) {
    char* p = ws + off;
    off += (bytes + 255) & ~(size_t)255;
    return p;
  };
  bf16_t* xn = (bf16_t*)alloc((size_t)T_TOK * 768 * 2);
  char* qm = alloc((size_t)T_TOK * 3072 * 2);  // qkv[2304] + mix[768]; reused as h
  bf16_t* qkv = (bf16_t*)qm;
  bf16_t* mixb = (bf16_t*)(qm + (size_t)T_TOK * 2304 * 2);
  bf16_t* h = (bf16_t*)qm;
  bf16_t* Wqkvt = (bf16_t*)alloc((size_t)2304 * 768 * 2);
  bf16_t* Wot = (bf16_t*)alloc((size_t)768 * 768 * 2);
  bf16_t* W1t = (bf16_t*)alloc((size_t)3072 * 768 * 2);
  bf16_t* W2t = (bf16_t*)alloc((size_t)768 * 3072 * 2);
  float* bqkv = (float*)alloc(2304 * 4);
  // optional bf16 residual-2 stream (saves ~115MB of HBM traffic); fall back
  // to the f32-in-d_out path if the workspace is too small. ws_size is fixed
  // across calls -> deterministic.
  const size_t x2_bytes = (size_t)T_TOK * 768 * 2;
  const bool bigws = (off + x2_bytes + 256 <= ws_size);
  bf16_t* x2b = (bf16_t*)alloc(x2_bytes);
  float* x2f = (float*)d_out;  // fallback: residual stream 2 in d_out (f32)

  dim3 tb(32, 8);
  wprep_k<<<6913, tb, 0, stream>>>(Wq, Wk, Wv, Wo, W1, W2, bq, bk, bv, Wqkvt,
                                   Wot, W1t, W2t, bqkv);

  ln_k<0><<<T_TOK / 4, 256, 0, stream>>>(x, g1, be1, xn);
  gemm_bt<0, 128, 128><<<dim3(2304 / 128, T_TOK / 128), 256, 0, stream>>>(
      xn, Wqkvt, bqkv, nullptr, qkv, 768, 2304);
  attn_k<<<128 * NH, 256, 0, stream>>>(qkv, mixb);
  if (bigws) {
    gemm_bt<3, 128, 128><<<dim3(768 / 128, T_TOK / 128), 256, 0, stream>>>(
        mixb, Wot, bo, x, x2b, 768, 768);
    ln_k<1><<<T_TOK / 4, 256, 0, stream>>>(x2b, g2, be2, xn);
    gemm_bt<2, 128, 128><<<dim3(3072 / 128, T_TOK / 128), 256, 0, stream>>>(
        xn, W1t, b1, nullptr, h, 768, 3072);
    gemm_bt<4, 128, 128><<<dim3(768 / 128, T_TOK / 128), 256, 0, stream>>>(
        h, W2t, b2, x2b, (float*)d_out, 3072, 768);
  } else {
    gemm_bt<1, 128, 128><<<dim3(768 / 128, T_TOK / 128), 256, 0, stream>>>(
        mixb, Wot, bo, x, x2f, 768, 768);
    ln_k<0><<<T_TOK / 4, 256, 0, stream>>>(x2f, g2, be2, xn);
    gemm_bt<2, 128, 128><<<dim3(3072 / 128, T_TOK / 128), 256, 0, stream>>>(
        xn, W1t, b1, nullptr, h, 768, 3072);
    gemm_bt<1, 128, 128><<<dim3(768 / 128, T_TOK / 128), 256, 0, stream>>>(
        h, W2t, b2, x2f, (float*)d_out, 3072, 768);
  }
}